// Round 1
// baseline (811.497 us; speedup 1.0000x reference)
//
#include <hip/hip_runtime.h>
#include <math.h>

#define N_NODES  50000
#define N_EDGES  800000
#define E_TOT    850000        // N_EDGES + N_NODES self loops
#define N_GRAPHS 128
#define F_IN     36
#define NH1      10
#define C1       36
#define D1       360           // NH1*C1
#define D2       128

#define SCHUNK  512
#define NCHUNK  98             // ceil(50000/512)

// ---------------- init ----------------
__global__ void k_init(int* counts, int* gstart, int* gend) {
  int i = blockIdx.x * blockDim.x + threadIdx.x;
  if (i < N_NODES) counts[i] = 0;
  if (i < N_GRAPHS) { gstart[i] = 0; gend[i] = 0; }
}

// ---------------- dst histogram ----------------
__global__ void k_hist(const int* ei, int* counts) {
  int e = blockIdx.x * blockDim.x + threadIdx.x;
  if (e >= E_TOT) return;
  int d = (e < N_EDGES) ? ei[N_EDGES + e] : (e - N_EDGES);
  atomicAdd(&counts[d], 1);
}

// ---------------- scan (3 kernels) ----------------
__global__ void k_scan1(const int* counts, int* partial) {
  __shared__ int red[256];
  int b = blockIdx.x, t = threadIdx.x;
  int base = b * SCHUNK;
  int v = 0;
  int i0 = base + t, i1 = base + t + 256;
  if (i0 < N_NODES) v += counts[i0];
  if (i1 < N_NODES) v += counts[i1];
  red[t] = v; __syncthreads();
  for (int off = 128; off; off >>= 1) {
    if (t < off) red[t] += red[t + off];
    __syncthreads();
  }
  if (t == 0) partial[b] = red[0];
}

__global__ void k_scan2(const int* partial, int* chunk_off, int* row_ptr) {
  if (threadIdx.x == 0 && blockIdx.x == 0) {
    int acc = 0;
    for (int i = 0; i < NCHUNK; i++) { chunk_off[i] = acc; acc += partial[i]; }
    row_ptr[N_NODES] = acc;
  }
}

__global__ void k_scan3(const int* counts, const int* chunk_off, int* row_ptr, int* nxt) {
  __shared__ int tmp[SCHUNK];
  int b = blockIdx.x, t = threadIdx.x;
  int i = b * SCHUNK + t;
  int v = (i < N_NODES) ? counts[i] : 0;
  tmp[t] = v; __syncthreads();
  for (int off = 1; off < SCHUNK; off <<= 1) {
    int x = (t >= off) ? tmp[t - off] : 0;
    __syncthreads();
    tmp[t] += x;
    __syncthreads();
  }
  if (i < N_NODES) {
    int excl = chunk_off[b] + tmp[t] - v;   // exclusive prefix
    row_ptr[i] = excl;
    nxt[i] = excl;
  }
}

// ---------------- scatter edges into CSR by dst ----------------
__global__ void k_scatter(const int* ei, int* nxt, int* csr_src) {
  int e = blockIdx.x * blockDim.x + threadIdx.x;
  if (e >= E_TOT) return;
  int s, d;
  if (e < N_EDGES) { s = ei[e]; d = ei[N_EDGES + e]; }
  else             { s = d = e - N_EDGES; }
  int pos = atomicAdd(&nxt[d], 1);
  csr_src[pos] = s;
}

// ---------------- GEMM1: h1 = x @ W1  [N,360] ----------------
#define G1_NPB 16
__global__ void k_gemm1(const float* __restrict__ x, const float* __restrict__ W1,
                        float* __restrict__ h1) {
  __shared__ float xs[G1_NPB][F_IN];
  int nb = blockIdx.x * G1_NPB;
  int t = threadIdx.x;  // 384 threads
  for (int i = t; i < G1_NPB * F_IN; i += 384) {
    int n = i / F_IN, k = i - n * F_IN;
    xs[n][k] = (nb + n < N_NODES) ? x[(size_t)(nb + n) * F_IN + k] : 0.f;
  }
  __syncthreads();
  if (t < D1) {
    float acc[G1_NPB];
#pragma unroll
    for (int i = 0; i < G1_NPB; i++) acc[i] = 0.f;
    for (int k = 0; k < F_IN; k++) {
      float w = W1[k * D1 + t];
#pragma unroll
      for (int i = 0; i < G1_NPB; i++) acc[i] = fmaf(xs[i][k], w, acc[i]);
    }
    for (int i = 0; i < G1_NPB; i++)
      if (nb + i < N_NODES) h1[(size_t)(nb + i) * D1 + t] = acc[i];
  }
}

// ---------------- attention scalars, layer 1 ----------------
__global__ void k_als1(const float* __restrict__ h1, const float* __restrict__ asrc,
                       const float* __restrict__ adst, float* als, float* ald) {
  int node = blockIdx.x * 4 + (threadIdx.x >> 6);
  int lane = threadIdx.x & 63;
  if (node >= N_NODES) return;
  const float* hr = h1 + (size_t)node * D1;
  for (int h = 0; h < NH1; h++) {
    float ps = 0.f, pd = 0.f;
    if (lane < C1) {
      float hv = hr[h * C1 + lane];
      ps = hv * asrc[h * C1 + lane];
      pd = hv * adst[h * C1 + lane];
    }
#pragma unroll
    for (int off = 32; off; off >>= 1) {
      ps += __shfl_xor(ps, off);
      pd += __shfl_xor(pd, off);
    }
    if (lane == 0) { als[node * NH1 + h] = ps; ald[node * NH1 + h] = pd; }
  }
}

// ---------------- layer-1 fused softmax + aggregate (per node, 1 wave) ----------------
__global__ __launch_bounds__(64)
void k_agg1(const float* __restrict__ h1, const float* __restrict__ als,
            const float* __restrict__ ald, const int* __restrict__ row_ptr,
            const int* __restrict__ csr_src, const float* __restrict__ b1,
            float* __restrict__ hact) {
  int node = blockIdx.x;
  int lane = threadIdx.x;
  int beg = row_ptr[node], end = row_ptr[node + 1];

  float acc[6];
#pragma unroll
  for (int j = 0; j < 6; j++) acc[j] = 0.f;
  int hd[6];
#pragma unroll
  for (int j = 0; j < 6; j++) {
    int slot = lane + 64 * j;
    int hh = slot / C1;
    hd[j] = hh < NH1 ? hh : NH1 - 1;
  }
  bool v5 = (lane < D1 - 320);  // lane<40: slot lane+320 valid

  float m[NH1], s[NH1], aldn[NH1];
#pragma unroll
  for (int h = 0; h < NH1; h++) { m[h] = -INFINITY; s[h] = 0.f; aldn[h] = ald[node * NH1 + h]; }

  __shared__ float pl[64][NH1];
  __shared__ int ssrc[64];

  for (int base = beg; base < end; base += 64) {
    int cnt = min(64, end - base);
    float el[NH1];
    int msrc = 0;
    if (lane < cnt) {
      msrc = csr_src[base + lane];
#pragma unroll
      for (int h = 0; h < NH1; h++) {
        float vv = als[msrc * NH1 + h] + aldn[h];
        el[h] = vv > 0.f ? vv : 0.2f * vv;
      }
    } else {
#pragma unroll
      for (int h = 0; h < NH1; h++) el[h] = -INFINITY;
    }
    ssrc[lane] = msrc;

    float nm[NH1], sc[NH1];
#pragma unroll
    for (int h = 0; h < NH1; h++) {
      float vv = el[h];
#pragma unroll
      for (int off = 32; off; off >>= 1) vv = fmaxf(vv, __shfl_xor(vv, off));
      nm[h] = fmaxf(m[h], vv);
      sc[h] = expf(m[h] - nm[h]);   // first chunk: exp(-inf)=0
      s[h] *= sc[h];
      m[h] = nm[h];
    }
#pragma unroll
    for (int j = 0; j < 6; j++) acc[j] *= sc[hd[j]];

#pragma unroll
    for (int h = 0; h < NH1; h++) {
      float pv = (lane < cnt) ? expf(el[h] - nm[h]) : 0.f;
      pl[lane][h] = pv;
      float t2 = pv;
#pragma unroll
      for (int off = 32; off; off >>= 1) t2 += __shfl_xor(t2, off);
      s[h] += t2;
    }
    __syncthreads();

    for (int j2 = 0; j2 < cnt; j2++) {
      const float* hr = h1 + (size_t)ssrc[j2] * D1;
#pragma unroll
      for (int j = 0; j < 6; j++) {
        if (j < 5 || v5)
          acc[j] = fmaf(pl[j2][hd[j]], hr[lane + 64 * j], acc[j]);
      }
    }
    __syncthreads();
  }

#pragma unroll
  for (int j = 0; j < 6; j++) {
    int slot = lane + 64 * j;
    if (slot < D1) {
      float val = acc[j] / (s[hd[j]] + 1e-16f) + b1[slot];
      hact[(size_t)node * D1 + slot] = val > 0.f ? val : (expf(val) - 1.f);  // ELU
    }
  }
}

// ---------------- GEMM2: h2 = hact @ W2  [N,128] ----------------
#define G2_NPB 16
__global__ void k_gemm2(const float* __restrict__ hact, const float* __restrict__ W2,
                        float* __restrict__ h2) {
  __shared__ float hs[G2_NPB][D1];  // 23 KB
  int nb = blockIdx.x * G2_NPB;
  int t = threadIdx.x;  // 256
  for (int i = t; i < G2_NPB * D1; i += 256) {
    int n = i / D1, k = i - n * D1;
    hs[n][k] = (nb + n < N_NODES) ? hact[(size_t)(nb + n) * D1 + k] : 0.f;
  }
  __syncthreads();
  int col = t & 127, ng = t >> 7;
  float acc[8];
#pragma unroll
  for (int i = 0; i < 8; i++) acc[i] = 0.f;
  for (int k = 0; k < D1; k++) {
    float w = W2[k * D2 + col];
#pragma unroll
    for (int i = 0; i < 8; i++) acc[i] = fmaf(hs[ng * 8 + i][k], w, acc[i]);
  }
  for (int i = 0; i < 8; i++) {
    int n = nb + ng * 8 + i;
    if (n < N_NODES) h2[(size_t)n * D2 + col] = acc[i];
  }
}

// ---------------- attention scalars, layer 2 ----------------
__global__ void k_als2(const float* __restrict__ h2, const float* __restrict__ asrc,
                       const float* __restrict__ adst, float* als, float* ald) {
  int node = blockIdx.x * 4 + (threadIdx.x >> 6);
  int lane = threadIdx.x & 63;
  if (node >= N_NODES) return;
  const float* hr = h2 + (size_t)node * D2;
  float ps = hr[lane] * asrc[lane] + hr[lane + 64] * asrc[lane + 64];
  float pd = hr[lane] * adst[lane] + hr[lane + 64] * adst[lane + 64];
#pragma unroll
  for (int off = 32; off; off >>= 1) { ps += __shfl_xor(ps, off); pd += __shfl_xor(pd, off); }
  if (lane == 0) { als[node] = ps; ald[node] = pd; }
}

// ---------------- layer-2 fused softmax + aggregate ----------------
__global__ __launch_bounds__(64)
void k_agg2(const float* __restrict__ h2, const float* __restrict__ als,
            const float* __restrict__ ald, const int* __restrict__ row_ptr,
            const int* __restrict__ csr_src, const float* __restrict__ b2,
            float* __restrict__ h3) {
  int node = blockIdx.x, lane = threadIdx.x;
  int beg = row_ptr[node], end = row_ptr[node + 1];
  float acc0 = 0.f, acc1 = 0.f, m = -INFINITY, s = 0.f;
  float aldn = ald[node];
  __shared__ float pl[64];
  __shared__ int ssrc[64];
  for (int base = beg; base < end; base += 64) {
    int cnt = min(64, end - base);
    float el = -INFINITY;
    int msrc = 0;
    if (lane < cnt) {
      msrc = csr_src[base + lane];
      float vv = als[msrc] + aldn;
      el = vv > 0.f ? vv : 0.2f * vv;
    }
    ssrc[lane] = msrc;
    float vv = el;
#pragma unroll
    for (int off = 32; off; off >>= 1) vv = fmaxf(vv, __shfl_xor(vv, off));
    float nm = fmaxf(m, vv);
    float sc = expf(m - nm);
    s *= sc; acc0 *= sc; acc1 *= sc; m = nm;
    float p = (lane < cnt) ? expf(el - nm) : 0.f;
    pl[lane] = p;
    float t2 = p;
#pragma unroll
    for (int off = 32; off; off >>= 1) t2 += __shfl_xor(t2, off);
    s += t2;
    __syncthreads();
    for (int j2 = 0; j2 < cnt; j2++) {
      const float* hr = h2 + (size_t)ssrc[j2] * D2;
      float a = pl[j2];
      acc0 = fmaf(a, hr[lane], acc0);
      acc1 = fmaf(a, hr[lane + 64], acc1);
    }
    __syncthreads();
  }
  float inv = 1.f / (s + 1e-16f);
  float v0 = acc0 * inv + b2[lane];
  float v1 = acc1 * inv + b2[lane + 64];
  h3[(size_t)node * D2 + lane]      = v0 > 0.f ? v0 : 0.f;   // ReLU
  h3[(size_t)node * D2 + lane + 64] = v1 > 0.f ? v1 : 0.f;
}

// ---------------- graph ranges (batch is sorted) ----------------
__global__ void k_bounds(const int* batch, int* gstart, int* gend) {
  int n = blockIdx.x * blockDim.x + threadIdx.x;
  if (n >= N_NODES) return;
  int g = batch[n];
  if (n == 0 || batch[n - 1] != g) gstart[g] = n;
  if (n == N_NODES - 1 || batch[n + 1] != g) gend[g] = n + 1;
}

// ---------------- global max pool ----------------
__global__ void k_pool(const float* __restrict__ h3, const int* gstart, const int* gend,
                       float* pool) {
  int g = blockIdx.x, c = threadIdx.x;
  int a = gstart[g], b = gend[g];
  float mx = -INFINITY;
  for (int n = a; n < b; n++) mx = fmaxf(mx, h3[(size_t)n * D2 + c]);
  pool[g * D2 + c] = (b > a) ? mx : 0.f;
}

// ---------------- final FC + relu ----------------
__global__ void k_final(const float* __restrict__ pool, const float* __restrict__ fcw,
                        const float* __restrict__ fcb, float* __restrict__ out) {
  __shared__ float ps[D2];
  int g = blockIdx.x, j = threadIdx.x;
  ps[j] = pool[g * D2 + j];
  __syncthreads();
  float acc = 0.f;
  for (int c = 0; c < D2; c++) acc = fmaf(ps[c], fcw[c * D2 + j], acc);
  acc += fcb[j];
  out[g * D2 + j] = acc > 0.f ? acc : 0.f;
}

extern "C" void kernel_launch(void* const* d_in, const int* in_sizes, int n_in,
                              void* d_out, int out_size, void* d_ws, size_t ws_size,
                              hipStream_t stream) {
  const float* x     = (const float*)d_in[0];
  const int*   ei    = (const int*)d_in[1];
  const int*   batch = (const int*)d_in[2];
  const float* W1    = (const float*)d_in[3];
  const float* asrc1 = (const float*)d_in[4];
  const float* adst1 = (const float*)d_in[5];
  const float* b1    = (const float*)d_in[6];
  const float* W2    = (const float*)d_in[7];
  const float* asrc2 = (const float*)d_in[8];
  const float* adst2 = (const float*)d_in[9];
  const float* b2    = (const float*)d_in[10];
  const float* fcw   = (const float*)d_in[11];
  const float* fcb   = (const float*)d_in[12];
  float* out = (float*)d_out;

  char* w = (char*)d_ws;
  size_t off = 0;
  auto alloc = [&](size_t bytes) -> char* {
    char* p = w + off;
    off = (off + bytes + 255) & ~(size_t)255;
    return p;
  };
  int* counts    = (int*)alloc((size_t)N_NODES * 4);
  int* row_ptr   = (int*)alloc((size_t)(N_NODES + 1) * 4);
  int* nxt       = (int*)alloc((size_t)N_NODES * 4);
  int* csr_src   = (int*)alloc((size_t)E_TOT * 4);
  int* partial   = (int*)alloc(NCHUNK * 4);
  int* chunk_off = (int*)alloc(NCHUNK * 4);
  int* gstart    = (int*)alloc(N_GRAPHS * 4);
  int* gend      = (int*)alloc(N_GRAPHS * 4);
  float* als1    = (float*)alloc((size_t)N_NODES * NH1 * 4);
  float* ald1    = (float*)alloc((size_t)N_NODES * NH1 * 4);
  float* als2    = (float*)alloc((size_t)N_NODES * 4);
  float* ald2    = (float*)alloc((size_t)N_NODES * 4);
  float* pool    = (float*)alloc((size_t)N_GRAPHS * D2 * 4);
  float* hact    = (float*)alloc((size_t)N_NODES * D1 * 4);
  float* h1      = (float*)alloc((size_t)N_NODES * D1 * 4);
  // h1 is dead after k_agg1 -> alias h2/h3 into its region
  float* h2 = h1;
  float* h3 = h1 + (size_t)N_NODES * D2;

  k_init<<<dim3((N_NODES + 255) / 256), dim3(256), 0, stream>>>(counts, gstart, gend);
  k_hist<<<dim3((E_TOT + 255) / 256), dim3(256), 0, stream>>>(ei, counts);
  k_scan1<<<dim3(NCHUNK), dim3(256), 0, stream>>>(counts, partial);
  k_scan2<<<dim3(1), dim3(64), 0, stream>>>(partial, chunk_off, row_ptr);
  k_scan3<<<dim3(NCHUNK), dim3(SCHUNK), 0, stream>>>(counts, chunk_off, row_ptr, nxt);
  k_scatter<<<dim3((E_TOT + 255) / 256), dim3(256), 0, stream>>>(ei, nxt, csr_src);

  k_gemm1<<<dim3((N_NODES + G1_NPB - 1) / G1_NPB), dim3(384), 0, stream>>>(x, W1, h1);
  k_als1<<<dim3((N_NODES + 3) / 4), dim3(256), 0, stream>>>(h1, asrc1, adst1, als1, ald1);
  k_agg1<<<dim3(N_NODES), dim3(64), 0, stream>>>(h1, als1, ald1, row_ptr, csr_src, b1, hact);

  k_gemm2<<<dim3((N_NODES + G2_NPB - 1) / G2_NPB), dim3(256), 0, stream>>>(hact, W2, h2);
  k_als2<<<dim3((N_NODES + 3) / 4), dim3(256), 0, stream>>>(h2, asrc2, adst2, als2, ald2);
  k_agg2<<<dim3(N_NODES), dim3(64), 0, stream>>>(h2, als2, ald2, row_ptr, csr_src, b2, h3);

  k_bounds<<<dim3((N_NODES + 255) / 256), dim3(256), 0, stream>>>(batch, gstart, gend);
  k_pool<<<dim3(N_GRAPHS), dim3(D2), 0, stream>>>(h3, gstart, gend, pool);
  k_final<<<dim3(N_GRAPHS), dim3(D2), 0, stream>>>(pool, fcw, fcb, out);

  (void)in_sizes; (void)n_in; (void)out_size; (void)ws_size;
}

// Round 2
// 570.496 us; speedup vs baseline: 1.4224x; 1.4224x over previous
//
#include <hip/hip_runtime.h>
#include <hip/hip_fp16.h>
#include <math.h>

#define N_NODES  50000
#define N_EDGES  800000
#define E_TOT    850000        // N_EDGES + N_NODES self loops
#define N_GRAPHS 128
#define F_IN     36
#define NH1      10
#define C1       36
#define D1       360           // NH1*C1
#define D2       128

#define SCHUNK  512
#define NCHUNK  98             // ceil(50000/512)

typedef unsigned int u32;

#if defined(__has_builtin)
#if __has_builtin(__builtin_amdgcn_fdot2)
#define HAVE_FDOT2 1
#endif
#endif
#ifndef HAVE_FDOT2
#define HAVE_FDOT2 0
#endif

typedef _Float16 h2v __attribute__((ext_vector_type(2)));

static __device__ __forceinline__ float2 h2f(u32 u) {
  __half2 h = __builtin_bit_cast(__half2, u);
  return __half22float2(h);
}
static __device__ __forceinline__ u32 f2h2(float a, float b) {
  __half2 h = __floats2half2_rn(a, b);
  return __builtin_bit_cast(u32, h);
}

// ---------------- init ----------------
__global__ void k_init(int* counts, u32* pool) {
  int i = blockIdx.x * blockDim.x + threadIdx.x;
  if (i < N_NODES) counts[i] = 0;
  if (i < N_GRAPHS * D2) pool[i] = 0u;
}

// ---------------- dst histogram ----------------
__global__ void k_hist(const int* ei, int* counts) {
  int e = blockIdx.x * blockDim.x + threadIdx.x;
  if (e >= E_TOT) return;
  int d = (e < N_EDGES) ? ei[N_EDGES + e] : (e - N_EDGES);
  atomicAdd(&counts[d], 1);
}

// ---------------- scan (3 kernels) ----------------
__global__ void k_scan1(const int* counts, int* partial) {
  __shared__ int red[256];
  int b = blockIdx.x, t = threadIdx.x;
  int base = b * SCHUNK;
  int v = 0;
  int i0 = base + t, i1 = base + t + 256;
  if (i0 < N_NODES) v += counts[i0];
  if (i1 < N_NODES) v += counts[i1];
  red[t] = v; __syncthreads();
  for (int off = 128; off; off >>= 1) {
    if (t < off) red[t] += red[t + off];
    __syncthreads();
  }
  if (t == 0) partial[b] = red[0];
}

__global__ void k_scan2(const int* partial, int* chunk_off, int* row_ptr) {
  if (threadIdx.x == 0 && blockIdx.x == 0) {
    int acc = 0;
    for (int i = 0; i < NCHUNK; i++) { chunk_off[i] = acc; acc += partial[i]; }
    row_ptr[N_NODES] = acc;
  }
}

__global__ void k_scan3(const int* counts, const int* chunk_off, int* row_ptr, int* nxt) {
  __shared__ int tmp[SCHUNK];
  int b = blockIdx.x, t = threadIdx.x;
  int i = b * SCHUNK + t;
  int v = (i < N_NODES) ? counts[i] : 0;
  tmp[t] = v; __syncthreads();
  for (int off = 1; off < SCHUNK; off <<= 1) {
    int x = (t >= off) ? tmp[t - off] : 0;
    __syncthreads();
    tmp[t] += x;
    __syncthreads();
  }
  if (i < N_NODES) {
    int excl = chunk_off[b] + tmp[t] - v;   // exclusive prefix
    row_ptr[i] = excl;
    nxt[i] = excl;
  }
}

// ---------------- scatter edges into CSR by dst ----------------
__global__ void k_scatter(const int* ei, int* nxt, int* csr_src) {
  int e = blockIdx.x * blockDim.x + threadIdx.x;
  if (e >= E_TOT) return;
  int s, d;
  if (e < N_EDGES) { s = ei[e]; d = ei[N_EDGES + e]; }
  else             { s = d = e - N_EDGES; }
  int pos = atomicAdd(&nxt[d], 1);
  csr_src[pos] = s;
}

// ---------------- pack W2 into k-paired half2 ----------------
__global__ void k_packw2(const float* __restrict__ W2, u32* __restrict__ W2h) {
  int i = blockIdx.x * blockDim.x + threadIdx.x;
  if (i >= (D1 / 2) * D2) return;
  int kp = i / D2, col = i - kp * D2;
  W2h[i] = f2h2(W2[(2 * kp) * D2 + col], W2[(2 * kp + 1) * D2 + col]);
}

// ---------------- GEMM1: h1 = x @ W1  [N,360] fp16 out ----------------
#define G1_NPB 16
__global__ void k_gemm1(const float* __restrict__ x, const float* __restrict__ W1,
                        __half* __restrict__ h1h) {
  __shared__ float xs[F_IN][G1_NPB];
  int nb = blockIdx.x * G1_NPB;
  int t = threadIdx.x;  // 384 threads
  for (int i = t; i < G1_NPB * F_IN; i += 384) {
    int n = i / F_IN, k = i - n * F_IN;
    xs[k][n] = x[(size_t)(nb + n) * F_IN + k];
  }
  __syncthreads();
  if (t < D1) {
    float acc[G1_NPB];
#pragma unroll
    for (int i = 0; i < G1_NPB; i++) acc[i] = 0.f;
    for (int k = 0; k < F_IN; k++) {
      float wv = W1[k * D1 + t];
      float4 c0 = *(const float4*)&xs[k][0];
      float4 c1 = *(const float4*)&xs[k][4];
      float4 c2 = *(const float4*)&xs[k][8];
      float4 c3 = *(const float4*)&xs[k][12];
      acc[0] = fmaf(c0.x, wv, acc[0]);  acc[1] = fmaf(c0.y, wv, acc[1]);
      acc[2] = fmaf(c0.z, wv, acc[2]);  acc[3] = fmaf(c0.w, wv, acc[3]);
      acc[4] = fmaf(c1.x, wv, acc[4]);  acc[5] = fmaf(c1.y, wv, acc[5]);
      acc[6] = fmaf(c1.z, wv, acc[6]);  acc[7] = fmaf(c1.w, wv, acc[7]);
      acc[8] = fmaf(c2.x, wv, acc[8]);  acc[9] = fmaf(c2.y, wv, acc[9]);
      acc[10] = fmaf(c2.z, wv, acc[10]); acc[11] = fmaf(c2.w, wv, acc[11]);
      acc[12] = fmaf(c3.x, wv, acc[12]); acc[13] = fmaf(c3.y, wv, acc[13]);
      acc[14] = fmaf(c3.z, wv, acc[14]); acc[15] = fmaf(c3.w, wv, acc[15]);
    }
#pragma unroll
    for (int i = 0; i < G1_NPB; i++)
      h1h[(size_t)(nb + i) * D1 + t] = __float2half(acc[i]);
  }
}

// ---------------- attention scalars, layer 1 (reads fp16 h1) ----------------
__global__ void k_als1(const __half* __restrict__ h1h, const float* __restrict__ asrc,
                       const float* __restrict__ adst, float* als, float* ald) {
  int node = blockIdx.x * 4 + (threadIdx.x >> 6);
  int lane = threadIdx.x & 63;
  const __half* hr = h1h + (size_t)node * D1;
#pragma unroll
  for (int h = 0; h < NH1; h++) {
    float ps = 0.f, pd = 0.f;
    if (lane < C1) {
      float hv = __half2float(hr[h * C1 + lane]);
      ps = hv * asrc[h * C1 + lane];
      pd = hv * adst[h * C1 + lane];
    }
#pragma unroll
    for (int off = 32; off; off >>= 1) {
      ps += __shfl_xor(ps, off);
      pd += __shfl_xor(pd, off);
    }
    if (lane == 0) { als[node * NH1 + h] = ps; ald[node * NH1 + h] = pd; }
  }
}

// ---------------- layer-1 fused softmax + aggregate ----------------
// 4 independent waves/block (one node each), wave-private LDS, no block barrier.
__global__ __launch_bounds__(256)
void k_agg1(const __half* __restrict__ h1h, const float* __restrict__ als,
            const float* __restrict__ ald, const int* __restrict__ row_ptr,
            const int* __restrict__ csr_src, const float* __restrict__ b1,
            __half* __restrict__ hacth) {
  __shared__ float pl[4][64][NH1];
  __shared__ float invs[4][NH1];
  int w = threadIdx.x >> 6, lane = threadIdx.x & 63;
  int node = blockIdx.x * 4 + w;   // 50000 = 4*12500 exact
  int beg = row_ptr[node], end = row_ptr[node + 1];
  int h0 = lane / 18;
  int h1i = (lane + 64) / 18;
  bool v2 = lane < 52;             // dword slot lane+128 < 180
  int h2 = v2 ? (lane + 128) / 18 : 0;

  float aldn[NH1];
#pragma unroll
  for (int h = 0; h < NH1; h++) aldn[h] = ald[node * NH1 + h];
  float a0x = 0.f, a0y = 0.f, a1x = 0.f, a1y = 0.f, a2x = 0.f, a2y = 0.f;
  float s[NH1];
#pragma unroll
  for (int h = 0; h < NH1; h++) s[h] = 0.f;

  for (int base = beg; base < end; base += 64) {
    int cnt = min(64, end - base);
    int msrc = 0;
    float p[NH1];
    if (lane < cnt) {
      msrc = csr_src[base + lane];
      const float* ap = als + (size_t)msrc * NH1;
#pragma unroll
      for (int h = 0; h < NH1; h++) {
        float vv = ap[h] + aldn[h];
        vv = vv > 0.f ? vv : 0.2f * vv;     // leaky_relu
        p[h] = __expf(vv);                  // no max-shift: logits are O(1)
      }
    } else {
#pragma unroll
      for (int h = 0; h < NH1; h++) p[h] = 0.f;
    }
#pragma unroll
    for (int h = 0; h < NH1; h++) {
      pl[w][lane][h] = p[h];
      float t = p[h];
#pragma unroll
      for (int off = 32; off; off >>= 1) t += __shfl_xor(t, off);
      s[h] += t;
    }
    __builtin_amdgcn_wave_barrier();

    int j2 = 0;
    for (; j2 + 2 <= cnt; j2 += 2) {
      int sA = __shfl(msrc, j2), sB = __shfl(msrc, j2 + 1);
      const u32* ra = (const u32*)(h1h + (size_t)sA * D1);
      const u32* rb = (const u32*)(h1h + (size_t)sB * D1);
      u32 ua0 = ra[lane], ua1 = ra[lane + 64];
      u32 ub0 = rb[lane], ub1 = rb[lane + 64];
      u32 ua2 = 0, ub2 = 0;
      if (v2) { ua2 = ra[lane + 128]; ub2 = rb[lane + 128]; }
      const float* pA = pl[w][j2];
      const float* pB = pl[w][j2 + 1];
      float cA0 = pA[h0], cA1 = pA[h1i], cA2 = pA[h2];
      float cB0 = pB[h0], cB1 = pB[h1i], cB2 = pB[h2];
      float2 f;
      f = h2f(ua0); a0x = fmaf(cA0, f.x, a0x); a0y = fmaf(cA0, f.y, a0y);
      f = h2f(ua1); a1x = fmaf(cA1, f.x, a1x); a1y = fmaf(cA1, f.y, a1y);
      f = h2f(ua2); a2x = fmaf(cA2, f.x, a2x); a2y = fmaf(cA2, f.y, a2y);
      f = h2f(ub0); a0x = fmaf(cB0, f.x, a0x); a0y = fmaf(cB0, f.y, a0y);
      f = h2f(ub1); a1x = fmaf(cB1, f.x, a1x); a1y = fmaf(cB1, f.y, a1y);
      f = h2f(ub2); a2x = fmaf(cB2, f.x, a2x); a2y = fmaf(cB2, f.y, a2y);
    }
    if (j2 < cnt) {
      int sA = __shfl(msrc, j2);
      const u32* ra = (const u32*)(h1h + (size_t)sA * D1);
      u32 ua0 = ra[lane], ua1 = ra[lane + 64];
      u32 ua2 = 0;
      if (v2) ua2 = ra[lane + 128];
      const float* pA = pl[w][j2];
      float cA0 = pA[h0], cA1 = pA[h1i], cA2 = pA[h2];
      float2 f;
      f = h2f(ua0); a0x = fmaf(cA0, f.x, a0x); a0y = fmaf(cA0, f.y, a0y);
      f = h2f(ua1); a1x = fmaf(cA1, f.x, a1x); a1y = fmaf(cA1, f.y, a1y);
      f = h2f(ua2); a2x = fmaf(cA2, f.x, a2x); a2y = fmaf(cA2, f.y, a2y);
    }
    __builtin_amdgcn_wave_barrier();
  }

  if (lane == 0) {
#pragma unroll
    for (int h = 0; h < NH1; h++) invs[w][h] = 1.f / (s[h] + 1e-16f);
  }
  __builtin_amdgcn_wave_barrier();
  float i0 = invs[w][h0], i1 = invs[w][h1i], i2 = invs[w][h2];

  const float2* bp = (const float2*)b1;
  float2 b0 = bp[lane], b1v = bp[lane + 64];
  float2 b2v = v2 ? bp[lane + 128] : float2{0.f, 0.f};
  float v0x = a0x * i0 + b0.x,  v0y = a0y * i0 + b0.y;
  float v1x = a1x * i1 + b1v.x, v1y = a1y * i1 + b1v.y;
  float v2x = a2x * i2 + b2v.x, v2y = a2y * i2 + b2v.y;
  // ELU
  v0x = v0x > 0.f ? v0x : __expf(v0x) - 1.f;
  v0y = v0y > 0.f ? v0y : __expf(v0y) - 1.f;
  v1x = v1x > 0.f ? v1x : __expf(v1x) - 1.f;
  v1y = v1y > 0.f ? v1y : __expf(v1y) - 1.f;
  v2x = v2x > 0.f ? v2x : __expf(v2x) - 1.f;
  v2y = v2y > 0.f ? v2y : __expf(v2y) - 1.f;
  u32* orow = (u32*)(hacth + (size_t)node * D1);
  orow[lane] = f2h2(v0x, v0y);
  orow[lane + 64] = f2h2(v1x, v1y);
  if (v2) orow[lane + 128] = f2h2(v2x, v2y);
}

// ---------------- GEMM2: h2 = hact @ W2  [N,128] via dot2 ----------------
#define G2_NPB 16
__global__ __launch_bounds__(256)
void k_gemm2(const __half* __restrict__ hacth, const u32* __restrict__ W2h,
             __half* __restrict__ h2h) {
  __shared__ u32 hs2[D1 / 2][G2_NPB];   // k-pair-major, node minor: 11.5 KB
  int nb = blockIdx.x * G2_NPB;
  int t = threadIdx.x;  // 256
  for (int i = t; i < G2_NPB * (D1 / 2); i += 256) {
    int n = i / (D1 / 2), kp = i - n * (D1 / 2);
    hs2[kp][n] = ((const u32*)(hacth + (size_t)(nb + n) * D1))[kp];
  }
  __syncthreads();
  int col = t & 127, ng = t >> 7;  // ng in {0,1}, 8 nodes each
  float acc[8];
#pragma unroll
  for (int i = 0; i < 8; i++) acc[i] = 0.f;
#pragma unroll 2
  for (int kp = 0; kp < D1 / 2; kp++) {
    u32 wv = W2h[kp * D2 + col];
    uint4 r0 = *(const uint4*)&hs2[kp][ng * 8];
    uint4 r1 = *(const uint4*)&hs2[kp][ng * 8 + 4];
#if HAVE_FDOT2
    h2v wh = __builtin_bit_cast(h2v, wv);
    acc[0] = __builtin_amdgcn_fdot2(__builtin_bit_cast(h2v, r0.x), wh, acc[0], false);
    acc[1] = __builtin_amdgcn_fdot2(__builtin_bit_cast(h2v, r0.y), wh, acc[1], false);
    acc[2] = __builtin_amdgcn_fdot2(__builtin_bit_cast(h2v, r0.z), wh, acc[2], false);
    acc[3] = __builtin_amdgcn_fdot2(__builtin_bit_cast(h2v, r0.w), wh, acc[3], false);
    acc[4] = __builtin_amdgcn_fdot2(__builtin_bit_cast(h2v, r1.x), wh, acc[4], false);
    acc[5] = __builtin_amdgcn_fdot2(__builtin_bit_cast(h2v, r1.y), wh, acc[5], false);
    acc[6] = __builtin_amdgcn_fdot2(__builtin_bit_cast(h2v, r1.z), wh, acc[6], false);
    acc[7] = __builtin_amdgcn_fdot2(__builtin_bit_cast(h2v, r1.w), wh, acc[7], false);
#else
    float2 fw = h2f(wv);
    float2 f;
    f = h2f(r0.x); acc[0] = fmaf(f.x, fw.x, fmaf(f.y, fw.y, acc[0]));
    f = h2f(r0.y); acc[1] = fmaf(f.x, fw.x, fmaf(f.y, fw.y, acc[1]));
    f = h2f(r0.z); acc[2] = fmaf(f.x, fw.x, fmaf(f.y, fw.y, acc[2]));
    f = h2f(r0.w); acc[3] = fmaf(f.x, fw.x, fmaf(f.y, fw.y, acc[3]));
    f = h2f(r1.x); acc[4] = fmaf(f.x, fw.x, fmaf(f.y, fw.y, acc[4]));
    f = h2f(r1.y); acc[5] = fmaf(f.x, fw.x, fmaf(f.y, fw.y, acc[5]));
    f = h2f(r1.z); acc[6] = fmaf(f.x, fw.x, fmaf(f.y, fw.y, acc[6]));
    f = h2f(r1.w); acc[7] = fmaf(f.x, fw.x, fmaf(f.y, fw.y, acc[7]));
#endif
  }
#pragma unroll
  for (int i = 0; i < 8; i++)
    h2h[(size_t)(nb + ng * 8 + i) * D2 + col] = __float2half(acc[i]);
}

// ---------------- attention scalars, layer 2 ----------------
__global__ void k_als2(const __half* __restrict__ h2h, const float* __restrict__ asrc,
                       const float* __restrict__ adst, float* als, float* ald) {
  int node = blockIdx.x * 4 + (threadIdx.x >> 6);
  int lane = threadIdx.x & 63;
  const u32* hr = (const u32*)(h2h + (size_t)node * D2);
  float2 f = h2f(hr[lane]);
  float2 a = ((const float2*)asrc)[lane];
  float2 d = ((const float2*)adst)[lane];
  float ps = f.x * a.x + f.y * a.y;
  float pd = f.x * d.x + f.y * d.y;
#pragma unroll
  for (int off = 32; off; off >>= 1) { ps += __shfl_xor(ps, off); pd += __shfl_xor(pd, off); }
  if (lane == 0) { als[node] = ps; ald[node] = pd; }
}

// ---------------- layer-2 fused softmax + aggregate ----------------
__global__ __launch_bounds__(256)
void k_agg2(const __half* __restrict__ h2h, const float* __restrict__ als,
            const float* __restrict__ ald, const int* __restrict__ row_ptr,
            const int* __restrict__ csr_src, const float* __restrict__ b2,
            float* __restrict__ h3) {
  int w = threadIdx.x >> 6, lane = threadIdx.x & 63;
  int node = blockIdx.x * 4 + w;
  int beg = row_ptr[node], end = row_ptr[node + 1];
  float aldn = ald[node];
  float ax = 0.f, ay = 0.f, ssum = 0.f;
  for (int base = beg; base < end; base += 64) {
    int cnt = min(64, end - base);
    int msrc = 0; float p = 0.f;
    if (lane < cnt) {
      msrc = csr_src[base + lane];
      float vv = als[msrc] + aldn;
      vv = vv > 0.f ? vv : 0.2f * vv;
      p = __expf(vv);
    }
    float t = p;
#pragma unroll
    for (int off = 32; off; off >>= 1) t += __shfl_xor(t, off);
    ssum += t;
    int j2 = 0;
    for (; j2 + 2 <= cnt; j2 += 2) {
      int sA = __shfl(msrc, j2), sB = __shfl(msrc, j2 + 1);
      float cA = __shfl(p, j2), cB = __shfl(p, j2 + 1);
      u32 ua = ((const u32*)(h2h + (size_t)sA * D2))[lane];
      u32 ub = ((const u32*)(h2h + (size_t)sB * D2))[lane];
      float2 f = h2f(ua); ax = fmaf(cA, f.x, ax); ay = fmaf(cA, f.y, ay);
      f = h2f(ub); ax = fmaf(cB, f.x, ax); ay = fmaf(cB, f.y, ay);
    }
    if (j2 < cnt) {
      int sA = __shfl(msrc, j2);
      float cA = __shfl(p, j2);
      u32 ua = ((const u32*)(h2h + (size_t)sA * D2))[lane];
      float2 f = h2f(ua); ax = fmaf(cA, f.x, ax); ay = fmaf(cA, f.y, ay);
    }
  }
  float inv = 1.f / (ssum + 1e-16f);
  float2 bv = ((const float2*)b2)[lane];
  float vx = fmaxf(ax * inv + bv.x, 0.f);
  float vy = fmaxf(ay * inv + bv.y, 0.f);
  *(float2*)(h3 + (size_t)node * D2 + 2 * lane) = float2{vx, vy};
}

// ---------------- global max pool (chunked, atomicMax on uint; h3 >= 0) ----------------
#define POOL_CH 256
__global__ void k_pool(const float* __restrict__ h3, const int* __restrict__ batch,
                       u32* __restrict__ pool) {
  int c = threadIdx.x;  // 128
  int n0 = blockIdx.x * POOL_CH;
  int n1 = min(n0 + POOL_CH, N_NODES);
  int g = batch[n0];
  float mx = 0.f;
  for (int n = n0; n < n1; n++) {
    int gn = batch[n];
    if (gn != g) {
      atomicMax(&pool[g * D2 + c], __float_as_uint(mx));
      mx = 0.f; g = gn;
    }
    mx = fmaxf(mx, h3[(size_t)n * D2 + c]);
  }
  atomicMax(&pool[g * D2 + c], __float_as_uint(mx));
}

// ---------------- final FC + relu ----------------
__global__ void k_final(const float* __restrict__ pool, const float* __restrict__ fcw,
                        const float* __restrict__ fcb, float* __restrict__ out) {
  __shared__ float ps[D2];
  int g = blockIdx.x, j = threadIdx.x;
  ps[j] = pool[g * D2 + j];
  __syncthreads();
  float acc = 0.f;
  for (int c = 0; c < D2; c++) acc = fmaf(ps[c], fcw[c * D2 + j], acc);
  acc += fcb[j];
  out[g * D2 + j] = acc > 0.f ? acc : 0.f;
}

extern "C" void kernel_launch(void* const* d_in, const int* in_sizes, int n_in,
                              void* d_out, int out_size, void* d_ws, size_t ws_size,
                              hipStream_t stream) {
  const float* x     = (const float*)d_in[0];
  const int*   ei    = (const int*)d_in[1];
  const int*   batch = (const int*)d_in[2];
  const float* W1    = (const float*)d_in[3];
  const float* asrc1 = (const float*)d_in[4];
  const float* adst1 = (const float*)d_in[5];
  const float* b1    = (const float*)d_in[6];
  const float* W2    = (const float*)d_in[7];
  const float* asrc2 = (const float*)d_in[8];
  const float* adst2 = (const float*)d_in[9];
  const float* b2    = (const float*)d_in[10];
  const float* fcw   = (const float*)d_in[11];
  const float* fcb   = (const float*)d_in[12];
  float* out = (float*)d_out;

  char* w = (char*)d_ws;
  size_t off = 0;
  auto alloc = [&](size_t bytes) -> char* {
    char* p = w + off;
    off = (off + bytes + 255) & ~(size_t)255;
    return p;
  };
  int* counts    = (int*)alloc((size_t)N_NODES * 4);
  int* row_ptr   = (int*)alloc((size_t)(N_NODES + 1) * 4);
  int* nxt       = (int*)alloc((size_t)N_NODES * 4);
  int* csr_src   = (int*)alloc((size_t)E_TOT * 4);
  int* partial   = (int*)alloc(NCHUNK * 4);
  int* chunk_off = (int*)alloc(NCHUNK * 4);
  float* als1    = (float*)alloc((size_t)N_NODES * NH1 * 4);
  float* ald1    = (float*)alloc((size_t)N_NODES * NH1 * 4);
  float* als2    = (float*)alloc((size_t)N_NODES * 4);
  float* ald2    = (float*)alloc((size_t)N_NODES * 4);
  u32*   pool    = (u32*)alloc((size_t)N_GRAPHS * D2 * 4);
  u32*   W2h     = (u32*)alloc((size_t)(D1 / 2) * D2 * 4);
  __half* h1h    = (__half*)alloc((size_t)N_NODES * D1 * 2);
  __half* hacth  = (__half*)alloc((size_t)N_NODES * D1 * 2);
  __half* h2h    = (__half*)alloc((size_t)N_NODES * D2 * 2);
  float* h3      = (float*)alloc((size_t)N_NODES * D2 * 4);

  k_init<<<dim3(196), dim3(256), 0, stream>>>(counts, pool);
  k_hist<<<dim3((E_TOT + 255) / 256), dim3(256), 0, stream>>>(ei, counts);
  k_scan1<<<dim3(NCHUNK), dim3(256), 0, stream>>>(counts, partial);
  k_scan2<<<dim3(1), dim3(64), 0, stream>>>(partial, chunk_off, row_ptr);
  k_scan3<<<dim3(NCHUNK), dim3(SCHUNK), 0, stream>>>(counts, chunk_off, row_ptr, nxt);
  k_scatter<<<dim3((E_TOT + 255) / 256), dim3(256), 0, stream>>>(ei, nxt, csr_src);
  k_packw2<<<dim3(((D1 / 2) * D2 + 255) / 256), dim3(256), 0, stream>>>(W2, W2h);

  k_gemm1<<<dim3(N_NODES / G1_NPB), dim3(384), 0, stream>>>(x, W1, h1h);
  k_als1<<<dim3(N_NODES / 4), dim3(256), 0, stream>>>(h1h, asrc1, adst1, als1, ald1);
  k_agg1<<<dim3(N_NODES / 4), dim3(256), 0, stream>>>(h1h, als1, ald1, row_ptr, csr_src, b1, hacth);

  k_gemm2<<<dim3(N_NODES / G2_NPB), dim3(256), 0, stream>>>(hacth, W2h, h2h);
  k_als2<<<dim3(N_NODES / 4), dim3(256), 0, stream>>>(h2h, asrc2, adst2, als2, ald2);
  k_agg2<<<dim3(N_NODES / 4), dim3(256), 0, stream>>>(h2h, als2, ald2, row_ptr, csr_src, b2, h3);

  k_pool<<<dim3((N_NODES + POOL_CH - 1) / POOL_CH), dim3(D2), 0, stream>>>(h3, batch, pool);
  k_final<<<dim3(N_GRAPHS), dim3(D2), 0, stream>>>((const float*)pool, fcw, fcb, out);

  (void)in_sizes; (void)n_in; (void)out_size; (void)ws_size;
}

// Round 3
// 551.992 us; speedup vs baseline: 1.4701x; 1.0335x over previous
//
#include <hip/hip_runtime.h>
#include <hip/hip_fp16.h>
#include <math.h>

#define N_NODES  50000
#define N_EDGES  800000
#define E_TOT    850000        // N_EDGES + N_NODES self loops
#define N_GRAPHS 128
#define F_IN     36
#define NH1      10
#define C1       36
#define D1       360           // NH1*C1
#define D2       128

#define SCHUNK  512
#define NCHUNK  98             // ceil(50000/512)

typedef unsigned int u32;

#if defined(__has_builtin)
#if __has_builtin(__builtin_amdgcn_fdot2)
#define HAVE_FDOT2 1
#endif
#endif
#ifndef HAVE_FDOT2
#define HAVE_FDOT2 0
#endif

typedef _Float16 h2v __attribute__((ext_vector_type(2)));

static __device__ __forceinline__ float2 h2f(u32 u) {
  __half2 h = __builtin_bit_cast(__half2, u);
  return __half22float2(h);
}
static __device__ __forceinline__ u32 f2h2(float a, float b) {
  __half2 h = __floats2half2_rn(a, b);
  return __builtin_bit_cast(u32, h);
}
static __device__ __forceinline__ float dot2acc(u32 a, u32 b, float acc) {
#if HAVE_FDOT2
  return __builtin_amdgcn_fdot2(__builtin_bit_cast(h2v, a), __builtin_bit_cast(h2v, b), acc, false);
#else
  float2 fa = h2f(a), fb = h2f(b);
  return fmaf(fa.x, fb.x, fmaf(fa.y, fb.y, acc));
#endif
}

// ---------------- init ----------------
__global__ void k_init(int* counts, u32* pool) {
  int i = blockIdx.x * blockDim.x + threadIdx.x;
  if (i < N_NODES) counts[i] = 0;
  if (i < N_GRAPHS * D2) pool[i] = 0u;
}

// ---------------- dst histogram ----------------
__global__ void k_hist(const int* ei, int* counts) {
  int e = blockIdx.x * blockDim.x + threadIdx.x;
  if (e >= E_TOT) return;
  int d = (e < N_EDGES) ? ei[N_EDGES + e] : (e - N_EDGES);
  atomicAdd(&counts[d], 1);
}

// ---------------- scan (3 kernels) ----------------
__global__ void k_scan1(const int* counts, int* partial) {
  __shared__ int red[256];
  int b = blockIdx.x, t = threadIdx.x;
  int base = b * SCHUNK;
  int v = 0;
  int i0 = base + t, i1 = base + t + 256;
  if (i0 < N_NODES) v += counts[i0];
  if (i1 < N_NODES) v += counts[i1];
  red[t] = v; __syncthreads();
  for (int off = 128; off; off >>= 1) {
    if (t < off) red[t] += red[t + off];
    __syncthreads();
  }
  if (t == 0) partial[b] = red[0];
}

__global__ void k_scan2(const int* partial, int* chunk_off, int* row_ptr) {
  if (threadIdx.x == 0 && blockIdx.x == 0) {
    int acc = 0;
    for (int i = 0; i < NCHUNK; i++) { chunk_off[i] = acc; acc += partial[i]; }
    row_ptr[N_NODES] = acc;
  }
}

__global__ void k_scan3(const int* counts, const int* chunk_off, int* row_ptr, int* nxt) {
  __shared__ int tmp[SCHUNK];
  int b = blockIdx.x, t = threadIdx.x;
  int i = b * SCHUNK + t;
  int v = (i < N_NODES) ? counts[i] : 0;
  tmp[t] = v; __syncthreads();
  for (int off = 1; off < SCHUNK; off <<= 1) {
    int x = (t >= off) ? tmp[t - off] : 0;
    __syncthreads();
    tmp[t] += x;
    __syncthreads();
  }
  if (i < N_NODES) {
    int excl = chunk_off[b] + tmp[t] - v;   // exclusive prefix
    row_ptr[i] = excl;
    nxt[i] = excl;
  }
}

// ---------------- scatter edges into CSR by dst ----------------
__global__ void k_scatter(const int* ei, int* nxt, int* csr_src) {
  int e = blockIdx.x * blockDim.x + threadIdx.x;
  if (e >= E_TOT) return;
  int s, d;
  if (e < N_EDGES) { s = ei[e]; d = ei[N_EDGES + e]; }
  else             { s = d = e - N_EDGES; }
  int pos = atomicAdd(&nxt[d], 1);
  csr_src[pos] = s;
}

// ---------------- prep: w_als[h][k] = sum_c W1[k, h*36+c]*a_src[h,c] ----------------
__global__ void k_wals(const float* __restrict__ W1, const float* __restrict__ asrc,
                       const float* __restrict__ adst, float* w_als, float* w_ald) {
  int i = blockIdx.x * blockDim.x + threadIdx.x;
  if (i >= D1) return;
  int h = i / F_IN, k = i - h * F_IN;
  float sa = 0.f, sd = 0.f;
  for (int c = 0; c < C1; c++) {
    float wv = W1[k * D1 + h * C1 + c];
    sa = fmaf(wv, asrc[h * C1 + c], sa);
    sd = fmaf(wv, adst[h * C1 + c], sd);
  }
  w_als[i] = sa; w_ald[i] = sd;     // layout [h*36+k]
}

// ---------------- prep: W1 transposed + k-paired fp16: W1t2[hc][kp] ----------------
__global__ void k_w1t2(const float* __restrict__ W1, u32* __restrict__ W1t2) {
  int i = blockIdx.x * blockDim.x + threadIdx.x;
  if (i >= D1 * (F_IN / 2)) return;
  int hc = i / (F_IN / 2), kp = i - hc * (F_IN / 2);
  W1t2[i] = f2h2(W1[(2 * kp) * D1 + hc], W1[(2 * kp + 1) * D1 + hc]);
}

// ---------------- prep: x -> fp16 ----------------
__global__ void k_xh(const float* __restrict__ x, u32* __restrict__ xh2) {
  int i = blockIdx.x * blockDim.x + threadIdx.x;
  if (i >= N_NODES * F_IN / 2) return;
  xh2[i] = f2h2(x[2 * i], x[2 * i + 1]);
}

// ---------------- prep: pack W2 into k-paired half2 ----------------
__global__ void k_packw2(const float* __restrict__ W2, u32* __restrict__ W2h) {
  int i = blockIdx.x * blockDim.x + threadIdx.x;
  if (i >= (D1 / 2) * D2) return;
  int kp = i / D2, col = i - kp * D2;
  W2h[i] = f2h2(W2[(2 * kp) * D2 + col], W2[(2 * kp + 1) * D2 + col]);
}

// ---------------- attention scalars, layer 1: als[n,h] = x[n,:]·w_als[h,:] ----------------
__global__ __launch_bounds__(256)
void k_als1(const float* __restrict__ x, const float* __restrict__ w_als,
            const float* __restrict__ w_ald, float* als, float* ald) {
  __shared__ float xs[64][F_IN + 1];
  __shared__ float wa[D1], wd[D1];
  int t = threadIdx.x;
  int nb = blockIdx.x * 64;
  for (int i = t; i < D1; i += 256) { wa[i] = w_als[i]; wd[i] = w_ald[i]; }
  int lim = min(64, N_NODES - nb);
  for (int i = t; i < lim * F_IN; i += 256) {
    int n = i / F_IN, k = i - n * F_IN;
    xs[n][k] = x[(size_t)(nb + n) * F_IN + k];
  }
  __syncthreads();
  for (int pair = t; pair < lim * NH1; pair += 256) {
    int n = pair / NH1, h = pair - n * NH1;
    const float* xp = xs[n];
    const float* wap = &wa[h * F_IN];
    const float* wdp = &wd[h * F_IN];
    float sa = 0.f, sd = 0.f;
#pragma unroll
    for (int k = 0; k < F_IN; k++) {
      float xv = xp[k];
      sa = fmaf(xv, wap[k], sa);
      sd = fmaf(xv, wdp[k], sd);
    }
    als[(size_t)(nb + n) * NH1 + h] = sa;
    ald[(size_t)(nb + n) * NH1 + h] = sd;
  }
}

// ---------------- layer-1 fused softmax + x-aggregation (per node, 1 wave) ----------------
// agg[n,h,k] = (1/s_h) * sum_e alpha-num_eh * x[src_e, k]; slot layout slot=h*36+k
__global__ __launch_bounds__(256)
void k_agg1(const __half* __restrict__ xh, const float* __restrict__ als,
            const float* __restrict__ ald, const int* __restrict__ row_ptr,
            const int* __restrict__ csr_src, __half* __restrict__ aggxh) {
  __shared__ float pl[4][64][NH1];
  __shared__ int ssrc[4][64];
  int w = threadIdx.x >> 6, lane = threadIdx.x & 63;
  int node = blockIdx.x * 4 + w;     // 50000 = 4*12500 exact
  int beg = row_ptr[node], end = row_ptr[node + 1];

  int ch[6], hd[6];
#pragma unroll
  for (int j = 0; j < 6; j++) {
    int slot = lane + 64 * j;
    if (slot >= D1) slot = D1 - 1;
    hd[j] = slot / C1;
    ch[j] = slot - hd[j] * C1;
  }
  bool v5 = (lane < D1 - 320);       // lane<40

  float aldn[NH1];
#pragma unroll
  for (int h = 0; h < NH1; h++) aldn[h] = ald[(size_t)node * NH1 + h];
  float acc[6] = {0.f, 0.f, 0.f, 0.f, 0.f, 0.f};
  float sp[NH1];
#pragma unroll
  for (int h = 0; h < NH1; h++) sp[h] = 0.f;

  for (int base = beg; base < end; base += 64) {
    int cnt = min(64, end - base);
    float p[NH1];
    int msrc = 0;
    if (lane < cnt) {
      msrc = csr_src[base + lane];
      const float2* ap = (const float2*)(als + (size_t)msrc * NH1);
#pragma unroll
      for (int q = 0; q < 5; q++) {
        float2 v = ap[q];
        float v0 = v.x + aldn[2 * q];
        float v1 = v.y + aldn[2 * q + 1];
        v0 = v0 > 0.f ? v0 : 0.2f * v0;
        v1 = v1 > 0.f ? v1 : 0.2f * v1;
        p[2 * q] = __expf(v0);
        p[2 * q + 1] = __expf(v1);
      }
    } else {
#pragma unroll
      for (int h = 0; h < NH1; h++) p[h] = 0.f;
    }
#pragma unroll
    for (int h = 0; h < NH1; h++) sp[h] += p[h];
    ssrc[w][lane] = msrc;
    float2* plw = (float2*)pl[w][lane];
#pragma unroll
    for (int q = 0; q < 5; q++) plw[q] = float2{p[2 * q], p[2 * q + 1]};
    __builtin_amdgcn_wave_barrier();

    for (int j = 0; j < cnt; j++) {
      int srcj = ssrc[w][j];
      const __half* row = xh + (size_t)srcj * F_IN;
      const float* plj = pl[w][j];
#pragma unroll
      for (int jj = 0; jj < 6; jj++) {
        if (jj < 5 || v5) {
          float xv = __half2float(row[ch[jj]]);
          acc[jj] = fmaf(plj[hd[jj]], xv, acc[jj]);
        }
      }
    }
    __builtin_amdgcn_wave_barrier();
  }

  // reduce per-lane partial sums -> full softmax denominators
#pragma unroll
  for (int h = 0; h < NH1; h++) {
    float t = sp[h];
#pragma unroll
    for (int off = 32; off; off >>= 1) t += __shfl_xor(t, off);
    sp[h] = t;
  }
#pragma unroll
  for (int jj = 0; jj < 6; jj++) {
    if (jj < 5 || v5) {
      float inv = 1.f / (sp[hd[jj]] + 1e-16f);
      aggxh[(size_t)node * D1 + lane + 64 * jj] = __float2half(acc[jj] * inv);
    }
  }
}

// ---------------- mix1: hact[n,hc] = ELU( sum_k agg[n,h,k]*W1[k,hc] + b1[hc] ) ----------------
#define MIX_NPB 32
__global__ __launch_bounds__(384)
void k_mix1(const u32* __restrict__ aggx2, const u32* __restrict__ W1t2,
            const float* __restrict__ b1, __half* __restrict__ hact) {
  __shared__ u32 ag[MIX_NPB][D1 / 2 + 4];
  int t = threadIdx.x;
  int nb = blockIdx.x * MIX_NPB;
  int lim = min(MIX_NPB, N_NODES - nb);
  const u32* gsrc = aggx2 + (size_t)nb * (D1 / 2);
  for (int i = t; i < lim * (D1 / 2); i += 384) {
    int n = i / (D1 / 2), k = i - n * (D1 / 2);
    ag[n][k] = gsrc[i];
  }
  __syncthreads();
  if (t < D1) {
    int h = t / C1;
    u32 wreg[F_IN / 2];
#pragma unroll
    for (int kp = 0; kp < F_IN / 2; kp++) wreg[kp] = W1t2[t * (F_IN / 2) + kp];
    float bj = b1[t];
    for (int n = 0; n < lim; n++) {
      const u32* a = &ag[n][h * (F_IN / 2)];
      float acc2 = 0.f;
#pragma unroll
      for (int kp = 0; kp < F_IN / 2; kp++) acc2 = dot2acc(a[kp], wreg[kp], acc2);
      float val = acc2 + bj;
      val = val > 0.f ? val : __expf(val) - 1.f;   // ELU
      hact[(size_t)(nb + n) * D1 + t] = __float2half(val);
    }
  }
}

// ---------------- GEMM2: h2 = hact @ W2  [N,128] via dot2 ----------------
#define G2_NPB 16
__global__ __launch_bounds__(256)
void k_gemm2(const __half* __restrict__ hacth, const u32* __restrict__ W2h,
             __half* __restrict__ h2h) {
  __shared__ u32 hs2[D1 / 2][G2_NPB];   // k-pair-major, node minor
  int nb = blockIdx.x * G2_NPB;
  int t = threadIdx.x;  // 256
  for (int i = t; i < G2_NPB * (D1 / 2); i += 256) {
    int n = i / (D1 / 2), kp = i - n * (D1 / 2);
    hs2[kp][n] = ((const u32*)(hacth + (size_t)(nb + n) * D1))[kp];
  }
  __syncthreads();
  int col = t & 127, ng = t >> 7;
  float acc[8];
#pragma unroll
  for (int i = 0; i < 8; i++) acc[i] = 0.f;
#pragma unroll 2
  for (int kp = 0; kp < D1 / 2; kp++) {
    u32 wv = W2h[kp * D2 + col];
    uint4 r0 = *(const uint4*)&hs2[kp][ng * 8];
    uint4 r1 = *(const uint4*)&hs2[kp][ng * 8 + 4];
    acc[0] = dot2acc(r0.x, wv, acc[0]);
    acc[1] = dot2acc(r0.y, wv, acc[1]);
    acc[2] = dot2acc(r0.z, wv, acc[2]);
    acc[3] = dot2acc(r0.w, wv, acc[3]);
    acc[4] = dot2acc(r1.x, wv, acc[4]);
    acc[5] = dot2acc(r1.y, wv, acc[5]);
    acc[6] = dot2acc(r1.z, wv, acc[6]);
    acc[7] = dot2acc(r1.w, wv, acc[7]);
  }
#pragma unroll
  for (int i = 0; i < 8; i++)
    h2h[(size_t)(nb + ng * 8 + i) * D2 + col] = __float2half(acc[i]);
}

// ---------------- attention scalars, layer 2 ----------------
__global__ void k_als2(const __half* __restrict__ h2h, const float* __restrict__ asrc,
                       const float* __restrict__ adst, float* als, float* ald) {
  int node = blockIdx.x * 4 + (threadIdx.x >> 6);
  int lane = threadIdx.x & 63;
  const u32* hr = (const u32*)(h2h + (size_t)node * D2);
  float2 f = h2f(hr[lane]);
  float2 a = ((const float2*)asrc)[lane];
  float2 d = ((const float2*)adst)[lane];
  float ps = f.x * a.x + f.y * a.y;
  float pd = f.x * d.x + f.y * d.y;
#pragma unroll
  for (int off = 32; off; off >>= 1) { ps += __shfl_xor(ps, off); pd += __shfl_xor(pd, off); }
  if (lane == 0) { als[node] = ps; ald[node] = pd; }
}

// ---------------- layer-2 fused softmax + aggregate + ReLU + max-pool ----------------
__global__ __launch_bounds__(256)
void k_agg2(const __half* __restrict__ h2h, const float* __restrict__ als,
            const float* __restrict__ ald, const int* __restrict__ row_ptr,
            const int* __restrict__ csr_src, const float* __restrict__ b2,
            const int* __restrict__ batch, u32* __restrict__ pool) {
  int w = threadIdx.x >> 6, lane = threadIdx.x & 63;
  int node = blockIdx.x * 4 + w;
  int beg = row_ptr[node], end = row_ptr[node + 1];
  float aldn = ald[node];
  float ax = 0.f, ay = 0.f, ssum = 0.f;
  for (int base = beg; base < end; base += 64) {
    int cnt = min(64, end - base);
    int msrc = 0; float p = 0.f;
    if (lane < cnt) {
      msrc = csr_src[base + lane];
      float vv = als[msrc] + aldn;
      vv = vv > 0.f ? vv : 0.2f * vv;
      p = __expf(vv);
    }
    ssum += p;   // per-lane partial; reduced at end
    int j2 = 0;
    for (; j2 + 2 <= cnt; j2 += 2) {
      int sA = __shfl(msrc, j2), sB = __shfl(msrc, j2 + 1);
      float cA = __shfl(p, j2), cB = __shfl(p, j2 + 1);
      u32 ua = ((const u32*)(h2h + (size_t)sA * D2))[lane];
      u32 ub = ((const u32*)(h2h + (size_t)sB * D2))[lane];
      float2 f = h2f(ua); ax = fmaf(cA, f.x, ax); ay = fmaf(cA, f.y, ay);
      f = h2f(ub); ax = fmaf(cB, f.x, ax); ay = fmaf(cB, f.y, ay);
    }
    if (j2 < cnt) {
      int sA = __shfl(msrc, j2);
      float cA = __shfl(p, j2);
      u32 ua = ((const u32*)(h2h + (size_t)sA * D2))[lane];
      float2 f = h2f(ua); ax = fmaf(cA, f.x, ax); ay = fmaf(cA, f.y, ay);
    }
  }
  float t2 = ssum;
#pragma unroll
  for (int off = 32; off; off >>= 1) t2 += __shfl_xor(t2, off);
  float inv = 1.f / (t2 + 1e-16f);
  float2 bv = ((const float2*)b2)[lane];
  float vx = fmaxf(ax * inv + bv.x, 0.f);
  float vy = fmaxf(ay * inv + bv.y, 0.f);
  int g = batch[node];
  atomicMax(&pool[g * D2 + 2 * lane], __float_as_uint(vx));
  atomicMax(&pool[g * D2 + 2 * lane + 1], __float_as_uint(vy));
}

// ---------------- final FC + relu ----------------
__global__ void k_final(const float* __restrict__ pool, const float* __restrict__ fcw,
                        const float* __restrict__ fcb, float* __restrict__ out) {
  __shared__ float ps[D2];
  int g = blockIdx.x, j = threadIdx.x;
  ps[j] = pool[g * D2 + j];
  __syncthreads();
  float acc = 0.f;
  for (int c = 0; c < D2; c++) acc = fmaf(ps[c], fcw[c * D2 + j], acc);
  acc += fcb[j];
  out[g * D2 + j] = acc > 0.f ? acc : 0.f;
}

extern "C" void kernel_launch(void* const* d_in, const int* in_sizes, int n_in,
                              void* d_out, int out_size, void* d_ws, size_t ws_size,
                              hipStream_t stream) {
  const float* x     = (const float*)d_in[0];
  const int*   ei    = (const int*)d_in[1];
  const int*   batch = (const int*)d_in[2];
  const float* W1    = (const float*)d_in[3];
  const float* asrc1 = (const float*)d_in[4];
  const float* adst1 = (const float*)d_in[5];
  const float* b1    = (const float*)d_in[6];
  const float* W2    = (const float*)d_in[7];
  const float* asrc2 = (const float*)d_in[8];
  const float* adst2 = (const float*)d_in[9];
  const float* b2    = (const float*)d_in[10];
  const float* fcw   = (const float*)d_in[11];
  const float* fcb   = (const float*)d_in[12];
  float* out = (float*)d_out;

  char* w = (char*)d_ws;
  size_t off = 0;
  auto alloc = [&](size_t bytes) -> char* {
    char* p = w + off;
    off = (off + bytes + 255) & ~(size_t)255;
    return p;
  };
  int* counts    = (int*)alloc((size_t)N_NODES * 4);
  int* row_ptr   = (int*)alloc((size_t)(N_NODES + 1) * 4);
  int* nxt       = (int*)alloc((size_t)N_NODES * 4);
  int* csr_src   = (int*)alloc((size_t)E_TOT * 4);
  int* partial   = (int*)alloc(NCHUNK * 4);
  int* chunk_off = (int*)alloc(NCHUNK * 4);
  float* als1    = (float*)alloc((size_t)N_NODES * NH1 * 4);
  float* ald1    = (float*)alloc((size_t)N_NODES * NH1 * 4);
  float* als2    = (float*)alloc((size_t)N_NODES * 4);
  float* ald2    = (float*)alloc((size_t)N_NODES * 4);
  u32*   pool    = (u32*)alloc((size_t)N_GRAPHS * D2 * 4);
  float* w_als   = (float*)alloc((size_t)D1 * 4);
  float* w_ald   = (float*)alloc((size_t)D1 * 4);
  u32*   W1t2    = (u32*)alloc((size_t)D1 * (F_IN / 2) * 4);
  u32*   W2h     = (u32*)alloc((size_t)(D1 / 2) * D2 * 4);
  u32*   xh2     = (u32*)alloc((size_t)N_NODES * (F_IN / 2) * 4);
  u32*   aggx2   = (u32*)alloc((size_t)N_NODES * (D1 / 2) * 4);
  __half* hacth  = (__half*)alloc((size_t)N_NODES * D1 * 2);
  __half* h2h    = (__half*)alloc((size_t)N_NODES * D2 * 2);

  k_init<<<dim3(196), dim3(256), 0, stream>>>(counts, pool);
  k_hist<<<dim3((E_TOT + 255) / 256), dim3(256), 0, stream>>>(ei, counts);
  k_scan1<<<dim3(NCHUNK), dim3(256), 0, stream>>>(counts, partial);
  k_scan2<<<dim3(1), dim3(64), 0, stream>>>(partial, chunk_off, row_ptr);
  k_scan3<<<dim3(NCHUNK), dim3(SCHUNK), 0, stream>>>(counts, chunk_off, row_ptr, nxt);
  k_scatter<<<dim3((E_TOT + 255) / 256), dim3(256), 0, stream>>>(ei, nxt, csr_src);

  k_wals<<<dim3(2), dim3(256), 0, stream>>>(W1, asrc1, adst1, w_als, w_ald);
  k_w1t2<<<dim3((D1 * (F_IN / 2) + 255) / 256), dim3(256), 0, stream>>>(W1, W1t2);
  k_packw2<<<dim3(((D1 / 2) * D2 + 255) / 256), dim3(256), 0, stream>>>(W2, W2h);
  k_xh<<<dim3((N_NODES * F_IN / 2 + 255) / 256), dim3(256), 0, stream>>>(x, xh2);

  k_als1<<<dim3((N_NODES + 63) / 64), dim3(256), 0, stream>>>(x, w_als, w_ald, als1, ald1);
  k_agg1<<<dim3(N_NODES / 4), dim3(256), 0, stream>>>((const __half*)xh2, als1, ald1,
                                                      row_ptr, csr_src, (__half*)aggx2);
  k_mix1<<<dim3((N_NODES + MIX_NPB - 1) / MIX_NPB), dim3(384), 0, stream>>>(aggx2, W1t2, b1, hacth);

  k_gemm2<<<dim3(N_NODES / G2_NPB), dim3(256), 0, stream>>>(hacth, W2h, h2h);
  k_als2<<<dim3(N_NODES / 4), dim3(256), 0, stream>>>(h2h, asrc2, adst2, als2, ald2);
  k_agg2<<<dim3(N_NODES / 4), dim3(256), 0, stream>>>(h2h, als2, ald2, row_ptr, csr_src,
                                                      b2, batch, pool);

  k_final<<<dim3(N_GRAPHS), dim3(D2), 0, stream>>>((const float*)pool, fcw, fcb, out);

  (void)in_sizes; (void)n_in; (void)out_size; (void)ws_size;
}

// Round 5
// 481.180 us; speedup vs baseline: 1.6865x; 1.1472x over previous
//
#include <hip/hip_runtime.h>
#include <hip/hip_fp16.h>
#include <math.h>

#define N_NODES  50000
#define N_EDGES  800000
#define E_TOT    850000        // N_EDGES + N_NODES self loops
#define N_GRAPHS 128
#define F_IN     36
#define NH1      10
#define C1       36
#define D1       360           // NH1*C1
#define D2       128
#define XW       18            // u32 words per x row (36 halves)

#define SCHUNK  512
#define NCHUNK  98             // ceil(50000/512)

typedef unsigned int u32;

#if defined(__has_builtin)
#if __has_builtin(__builtin_amdgcn_fdot2)
#define HAVE_FDOT2 1
#endif
#endif
#ifndef HAVE_FDOT2
#define HAVE_FDOT2 0
#endif

typedef _Float16 h2v __attribute__((ext_vector_type(2)));

static __device__ __forceinline__ float2 h2f(u32 u) {
  __half2 h = __builtin_bit_cast(__half2, u);
  return __half22float2(h);
}
static __device__ __forceinline__ u32 f2h2(float a, float b) {
  __half2 h = __floats2half2_rn(a, b);
  return __builtin_bit_cast(u32, h);
}
static __device__ __forceinline__ float dot2acc(u32 a, u32 b, float acc) {
#if HAVE_FDOT2
  return __builtin_amdgcn_fdot2(__builtin_bit_cast(h2v, a), __builtin_bit_cast(h2v, b), acc, false);
#else
  float2 fa = h2f(a), fb = h2f(b);
  return fmaf(fa.x, fb.x, fmaf(fa.y, fb.y, acc));
#endif
}

// ---------------- init ----------------
__global__ void k_init(int* counts, u32* pool) {
  int i = blockIdx.x * blockDim.x + threadIdx.x;
  if (i < N_NODES) counts[i] = 0;
  if (i < N_GRAPHS * D2) pool[i] = 0u;
}

// ---------------- dst histogram ----------------
__global__ void k_hist(const int* ei, int* counts) {
  int e = blockIdx.x * blockDim.x + threadIdx.x;
  if (e >= E_TOT) return;
  int d = (e < N_EDGES) ? ei[N_EDGES + e] : (e - N_EDGES);
  atomicAdd(&counts[d], 1);
}

// ---------------- scan (3 kernels) ----------------
__global__ void k_scan1(const int* counts, int* partial) {
  __shared__ int red[256];
  int b = blockIdx.x, t = threadIdx.x;
  int base = b * SCHUNK;
  int v = 0;
  int i0 = base + t, i1 = base + t + 256;
  if (i0 < N_NODES) v += counts[i0];
  if (i1 < N_NODES) v += counts[i1];
  red[t] = v; __syncthreads();
  for (int off = 128; off; off >>= 1) {
    if (t < off) red[t] += red[t + off];
    __syncthreads();
  }
  if (t == 0) partial[b] = red[0];
}

__global__ void k_scan2(const int* partial, int* chunk_off, int* row_ptr) {
  if (threadIdx.x == 0 && blockIdx.x == 0) {
    int acc = 0;
    for (int i = 0; i < NCHUNK; i++) { chunk_off[i] = acc; acc += partial[i]; }
    row_ptr[N_NODES] = acc;
  }
}

__global__ void k_scan3(const int* counts, const int* chunk_off, int* row_ptr, int* nxt) {
  __shared__ int tmp[SCHUNK];
  int b = blockIdx.x, t = threadIdx.x;
  int i = b * SCHUNK + t;
  int v = (i < N_NODES) ? counts[i] : 0;
  tmp[t] = v; __syncthreads();
  for (int off = 1; off < SCHUNK; off <<= 1) {
    int x = (t >= off) ? tmp[t - off] : 0;
    __syncthreads();
    tmp[t] += x;
    __syncthreads();
  }
  if (i < N_NODES) {
    int excl = chunk_off[b] + tmp[t] - v;   // exclusive prefix
    row_ptr[i] = excl;
    nxt[i] = excl;
  }
}

// ---------------- scatter edges into CSR by dst ----------------
__global__ void k_scatter(const int* ei, int* nxt, int* csr_src) {
  int e = blockIdx.x * blockDim.x + threadIdx.x;
  if (e >= E_TOT) return;
  int s, d;
  if (e < N_EDGES) { s = ei[e]; d = ei[N_EDGES + e]; }
  else             { s = d = e - N_EDGES; }
  int pos = atomicAdd(&nxt[d], 1);
  csr_src[pos] = s;
}

// ---------------- merged weight prep: w_als/w_ald + W1t2 + W2h ----------------
// needs D1 + D1*18 + 180*128 = 29880 threads -> 117 blocks x 256
__global__ void k_prep(const float* __restrict__ W1, const float* __restrict__ asrc,
                       const float* __restrict__ adst, const float* __restrict__ W2,
                       float* w_als, float* w_ald, u32* W1t2, u32* W2h) {
  int id = blockIdx.x * blockDim.x + threadIdx.x;
  if (id < D1) {
    // w_als[h*36+k] = sum_c W1[k, h*36+c]*a_src[h,c]
    int h = id / F_IN, k = id - h * F_IN;
    float sa = 0.f, sd = 0.f;
    for (int c = 0; c < C1; c++) {
      float wv = W1[k * D1 + h * C1 + c];
      sa = fmaf(wv, asrc[h * C1 + c], sa);
      sd = fmaf(wv, adst[h * C1 + c], sd);
    }
    w_als[id] = sa; w_ald[id] = sd;
  } else if (id < D1 + D1 * (F_IN / 2)) {
    // W1 transposed + k-paired fp16: W1t2[hc][kp]
    int i = id - D1;
    int hc = i / (F_IN / 2), kp = i - hc * (F_IN / 2);
    W1t2[i] = f2h2(W1[(2 * kp) * D1 + hc], W1[(2 * kp + 1) * D1 + hc]);
  } else if (id < D1 + D1 * (F_IN / 2) + (D1 / 2) * D2) {
    // W2 k-paired fp16: W2h[kp][col]
    int i = id - D1 - D1 * (F_IN / 2);
    int kp = i / D2, col = i - kp * D2;
    W2h[i] = f2h2(W2[(2 * kp) * D2 + col], W2[(2 * kp + 1) * D2 + col]);
  }
}

// ---------------- layer-1 attention scalars + x fp16 pack ----------------
__global__ __launch_bounds__(256)
void k_als1(const float* __restrict__ x, const float* __restrict__ w_als,
            const float* __restrict__ w_ald, float* als, float* ald,
            u32* __restrict__ xh2) {
  __shared__ float xs[64][F_IN + 1];
  __shared__ float wa[D1], wd[D1];
  int t = threadIdx.x;
  int nb = blockIdx.x * 64;
  for (int i = t; i < D1; i += 256) { wa[i] = w_als[i]; wd[i] = w_ald[i]; }
  int lim = min(64, N_NODES - nb);
  for (int i = t; i < lim * F_IN; i += 256) {
    int n = i / F_IN, k = i - n * F_IN;
    xs[n][k] = x[(size_t)(nb + n) * F_IN + k];
  }
  __syncthreads();
  // pack x -> fp16 pairs
  for (int i = t; i < lim * XW; i += 256) {
    int n = i / XW, kp = i - n * XW;
    xh2[(size_t)(nb + n) * XW + kp] = f2h2(xs[n][2 * kp], xs[n][2 * kp + 1]);
  }
  for (int pair = t; pair < lim * NH1; pair += 256) {
    int n = pair / NH1, h = pair - n * NH1;
    const float* xp = xs[n];
    const float* wap = &wa[h * F_IN];
    const float* wdp = &wd[h * F_IN];
    float sa = 0.f, sd = 0.f;
#pragma unroll
    for (int k = 0; k < F_IN; k++) {
      float xv = xp[k];
      sa = fmaf(xv, wap[k], sa);
      sd = fmaf(xv, wdp[k], sd);
    }
    als[(size_t)(nb + n) * NH1 + h] = sa;
    ald[(size_t)(nb + n) * NH1 + h] = sd;
  }
}

// ---------------- layer-1 fused softmax + x-aggregation (per node, 1 wave) ----------------
// acc u32-slot s = h*18+kp (halves h*36+2kp, +1); lane owns s in {lane, lane+64, lane+128}
__global__ __launch_bounds__(256)
void k_agg1(const u32* __restrict__ xrow, const float* __restrict__ als,
            const float* __restrict__ ald, const int* __restrict__ row_ptr,
            const int* __restrict__ csr_src, u32* __restrict__ aggx2) {
  __shared__ float pl[4][64][NH1];
  int w = threadIdx.x >> 6, lane = threadIdx.x & 63;
  int node = blockIdx.x * 4 + w;     // 50000 = 4*12500 exact
  int beg = row_ptr[node], end = row_ptr[node + 1];

  int h0 = lane / XW,  kp0 = lane - XW * h0;
  int s1 = lane + 64;
  int h1i = s1 / XW,   kp1 = s1 - XW * h1i;
  bool v2 = lane < 52;               // slot lane+128 < 180
  int s2 = v2 ? lane + 128 : 179;
  int h2i = s2 / XW,   kp2 = s2 - XW * h2i;

  float aldn[NH1];
#pragma unroll
  for (int h = 0; h < NH1; h++) aldn[h] = ald[(size_t)node * NH1 + h];
  float a0x = 0.f, a0y = 0.f, a1x = 0.f, a1y = 0.f, a2x = 0.f, a2y = 0.f;
  float sp[NH1];
#pragma unroll
  for (int h = 0; h < NH1; h++) sp[h] = 0.f;

  for (int base = beg; base < end; base += 64) {
    int cnt = min(64, end - base);
    float p[NH1];
    int msrc = 0;
    if (lane < cnt) {
      msrc = csr_src[base + lane];
      const float2* ap = (const float2*)(als + (size_t)msrc * NH1);
#pragma unroll
      for (int q = 0; q < 5; q++) {
        float2 v = ap[q];
        float v0 = v.x + aldn[2 * q];
        float v1 = v.y + aldn[2 * q + 1];
        v0 = v0 > 0.f ? v0 : 0.2f * v0;     // leaky_relu
        v1 = v1 > 0.f ? v1 : 0.2f * v1;
        p[2 * q] = __expf(v0);              // no max-shift: logits O(1)
        p[2 * q + 1] = __expf(v1);
      }
    } else {
#pragma unroll
      for (int h = 0; h < NH1; h++) p[h] = 0.f;
    }
#pragma unroll
    for (int h = 0; h < NH1; h++) sp[h] += p[h];
    float2* plw = (float2*)pl[w][lane];
#pragma unroll
    for (int q = 0; q < 5; q++) plw[q] = float2{p[2 * q], p[2 * q + 1]};
    __builtin_amdgcn_wave_barrier();

    int j2 = 0;
    for (; j2 + 2 <= cnt; j2 += 2) {
      int sA = __shfl(msrc, j2), sB = __shfl(msrc, j2 + 1);
      const u32* ra = xrow + (size_t)sA * XW;
      const u32* rb = xrow + (size_t)sB * XW;
      u32 ua0 = ra[kp0], ua1 = ra[kp1], ua2 = ra[kp2];
      u32 ub0 = rb[kp0], ub1 = rb[kp1], ub2 = rb[kp2];
      const float* pA = pl[w][j2];
      const float* pB = pl[w][j2 + 1];
      float cA0 = pA[h0], cA1 = pA[h1i], cA2 = pA[h2i];
      float cB0 = pB[h0], cB1 = pB[h1i], cB2 = pB[h2i];
      float2 f;
      f = h2f(ua0); a0x = fmaf(cA0, f.x, a0x); a0y = fmaf(cA0, f.y, a0y);
      f = h2f(ua1); a1x = fmaf(cA1, f.x, a1x); a1y = fmaf(cA1, f.y, a1y);
      f = h2f(ua2); a2x = fmaf(cA2, f.x, a2x); a2y = fmaf(cA2, f.y, a2y);
      f = h2f(ub0); a0x = fmaf(cB0, f.x, a0x); a0y = fmaf(cB0, f.y, a0y);
      f = h2f(ub1); a1x = fmaf(cB1, f.x, a1x); a1y = fmaf(cB1, f.y, a1y);
      f = h2f(ub2); a2x = fmaf(cB2, f.x, a2x); a2y = fmaf(cB2, f.y, a2y);
    }
    if (j2 < cnt) {
      int sA = __shfl(msrc, j2);
      const u32* ra = xrow + (size_t)sA * XW;
      u32 ua0 = ra[kp0], ua1 = ra[kp1], ua2 = ra[kp2];
      const float* pA = pl[w][j2];
      float cA0 = pA[h0], cA1 = pA[h1i], cA2 = pA[h2i];
      float2 f;
      f = h2f(ua0); a0x = fmaf(cA0, f.x, a0x); a0y = fmaf(cA0, f.y, a0y);
      f = h2f(ua1); a1x = fmaf(cA1, f.x, a1x); a1y = fmaf(cA1, f.y, a1y);
      f = h2f(ua2); a2x = fmaf(cA2, f.x, a2x); a2y = fmaf(cA2, f.y, a2y);
    }
    __builtin_amdgcn_wave_barrier();
  }

  // reduce per-lane partial sums -> softmax denominators
#pragma unroll
  for (int h = 0; h < NH1; h++) {
    float t = sp[h];
#pragma unroll
    for (int off = 32; off; off >>= 1) t += __shfl_xor(t, off);
    sp[h] = t;
  }
  float i0 = 1.f / (sp[h0] + 1e-16f);
  float i1 = 1.f / (sp[h1i] + 1e-16f);
  float i2 = 1.f / (sp[h2i] + 1e-16f);
  u32* orow = aggx2 + (size_t)node * (D1 / 2);
  orow[lane] = f2h2(a0x * i0, a0y * i0);
  orow[lane + 64] = f2h2(a1x * i1, a1y * i1);
  if (v2) orow[lane + 128] = f2h2(a2x * i2, a2y * i2);
}

// ---------------- mix1: hact[n,hc] = ELU( sum_k agg[n,h,k]*W1[k,hc] + b1[hc] ) ----------------
#define MIX_NPB 32
__global__ __launch_bounds__(384)
void k_mix1(const u32* __restrict__ aggx2, const u32* __restrict__ W1t2,
            const float* __restrict__ b1, __half* __restrict__ hact) {
  __shared__ u32 ag[MIX_NPB][D1 / 2 + 4];
  int t = threadIdx.x;
  int nb = blockIdx.x * MIX_NPB;
  int lim = min(MIX_NPB, N_NODES - nb);
  const u32* gsrc = aggx2 + (size_t)nb * (D1 / 2);
  for (int i = t; i < lim * (D1 / 2); i += 384) {
    int n = i / (D1 / 2), k = i - n * (D1 / 2);
    ag[n][k] = gsrc[i];
  }
  __syncthreads();
  if (t < D1) {
    int h = t / C1;
    u32 wreg[F_IN / 2];
#pragma unroll
    for (int kp = 0; kp < F_IN / 2; kp++) wreg[kp] = W1t2[t * (F_IN / 2) + kp];
    float bj = b1[t];
    for (int n = 0; n < lim; n++) {
      const u32* a = &ag[n][h * (F_IN / 2)];
      float acc2 = 0.f;
#pragma unroll
      for (int kp = 0; kp < F_IN / 2; kp++) acc2 = dot2acc(a[kp], wreg[kp], acc2);
      float val = acc2 + bj;
      val = val > 0.f ? val : __expf(val) - 1.f;   // ELU
      hact[(size_t)(nb + n) * D1 + t] = __float2half(val);
    }
  }
}

// ---------------- GEMM2: h2 = hact @ W2  [N,128] via dot2 ----------------
#define G2_NPB 16
__global__ __launch_bounds__(256)
void k_gemm2(const __half* __restrict__ hacth, const u32* __restrict__ W2h,
             __half* __restrict__ h2h) {
  __shared__ u32 hs2[D1 / 2][G2_NPB];   // k-pair-major, node minor
  int nb = blockIdx.x * G2_NPB;
  int t = threadIdx.x;  // 256
  for (int i = t; i < G2_NPB * (D1 / 2); i += 256) {
    int n = i / (D1 / 2), kp = i - n * (D1 / 2);
    hs2[kp][n] = ((const u32*)(hacth + (size_t)(nb + n) * D1))[kp];
  }
  __syncthreads();
  int col = t & 127, ng = t >> 7;
  float acc[8];
#pragma unroll
  for (int i = 0; i < 8; i++) acc[i] = 0.f;
#pragma unroll 2
  for (int kp = 0; kp < D1 / 2; kp++) {
    u32 wv = W2h[kp * D2 + col];
    uint4 r0 = *(const uint4*)&hs2[kp][ng * 8];
    uint4 r1 = *(const uint4*)&hs2[kp][ng * 8 + 4];
    acc[0] = dot2acc(r0.x, wv, acc[0]);
    acc[1] = dot2acc(r0.y, wv, acc[1]);
    acc[2] = dot2acc(r0.z, wv, acc[2]);
    acc[3] = dot2acc(r0.w, wv, acc[3]);
    acc[4] = dot2acc(r1.x, wv, acc[4]);
    acc[5] = dot2acc(r1.y, wv, acc[5]);
    acc[6] = dot2acc(r1.z, wv, acc[6]);
    acc[7] = dot2acc(r1.w, wv, acc[7]);
  }
#pragma unroll
  for (int i = 0; i < 8; i++)
    h2h[(size_t)(nb + ng * 8 + i) * D2 + col] = __float2half(acc[i]);
}

// ---------------- attention scalars, layer 2 ----------------
__global__ void k_als2(const __half* __restrict__ h2h, const float* __restrict__ asrc,
                       const float* __restrict__ adst, float* als, float* ald) {
  int node = blockIdx.x * 4 + (threadIdx.x >> 6);
  int lane = threadIdx.x & 63;
  const u32* hr = (const u32*)(h2h + (size_t)node * D2);
  float2 f = h2f(hr[lane]);
  float2 a = ((const float2*)asrc)[lane];
  float2 d = ((const float2*)adst)[lane];
  float ps = f.x * a.x + f.y * a.y;
  float pd = f.x * d.x + f.y * d.y;
#pragma unroll
  for (int off = 32; off; off >>= 1) { ps += __shfl_xor(ps, off); pd += __shfl_xor(pd, off); }
  if (lane == 0) { als[node] = ps; ald[node] = pd; }
}

// ---------------- layer-2 fused softmax + aggregate + ReLU + max-pool ----------------
__global__ __launch_bounds__(256)
void k_agg2(const __half* __restrict__ h2h, const float* __restrict__ als,
            const float* __restrict__ ald, const int* __restrict__ row_ptr,
            const int* __restrict__ csr_src, const float* __restrict__ b2,
            const int* __restrict__ batch, u32* __restrict__ pool) {
  int w = threadIdx.x >> 6, lane = threadIdx.x & 63;
  int node = blockIdx.x * 4 + w;
  int beg = row_ptr[node], end = row_ptr[node + 1];
  float aldn = ald[node];
  float ax = 0.f, ay = 0.f, ssum = 0.f;
  for (int base = beg; base < end; base += 64) {
    int cnt = min(64, end - base);
    int msrc = 0; float p = 0.f;
    if (lane < cnt) {
      msrc = csr_src[base + lane];
      float vv = als[msrc] + aldn;
      vv = vv > 0.f ? vv : 0.2f * vv;
      p = __expf(vv);
    }
    ssum += p;   // per-lane partial; reduced at end
    int j2 = 0;
    for (; j2 + 2 <= cnt; j2 += 2) {
      int sA = __shfl(msrc, j2), sB = __shfl(msrc, j2 + 1);
      float cA = __shfl(p, j2), cB = __shfl(p, j2 + 1);
      u32 ua = ((const u32*)(h2h + (size_t)sA * D2))[lane];
      u32 ub = ((const u32*)(h2h + (size_t)sB * D2))[lane];
      float2 f = h2f(ua); ax = fmaf(cA, f.x, ax); ay = fmaf(cA, f.y, ay);
      f = h2f(ub); ax = fmaf(cB, f.x, ax); ay = fmaf(cB, f.y, ay);
    }
    if (j2 < cnt) {
      int sA = __shfl(msrc, j2);
      float cA = __shfl(p, j2);
      u32 ua = ((const u32*)(h2h + (size_t)sA * D2))[lane];
      float2 f = h2f(ua); ax = fmaf(cA, f.x, ax); ay = fmaf(cA, f.y, ay);
    }
  }
  float t2 = ssum;
#pragma unroll
  for (int off = 32; off; off >>= 1) t2 += __shfl_xor(t2, off);
  float inv = 1.f / (t2 + 1e-16f);
  float2 bv = ((const float2*)b2)[lane];
  float vx = fmaxf(ax * inv + bv.x, 0.f);
  float vy = fmaxf(ay * inv + bv.y, 0.f);
  int g = batch[node];
  atomicMax(&pool[g * D2 + 2 * lane], __float_as_uint(vx));
  atomicMax(&pool[g * D2 + 2 * lane + 1], __float_as_uint(vy));
}

// ---------------- final FC + relu ----------------
__global__ void k_final(const float* __restrict__ pool, const float* __restrict__ fcw,
                        const float* __restrict__ fcb, float* __restrict__ out) {
  __shared__ float ps[D2];
  int g = blockIdx.x, j = threadIdx.x;
  ps[j] = pool[g * D2 + j];
  __syncthreads();
  float acc = 0.f;
  for (int c = 0; c < D2; c++) acc = fmaf(ps[c], fcw[c * D2 + j], acc);
  acc += fcb[j];
  out[g * D2 + j] = acc > 0.f ? acc : 0.f;
}

extern "C" void kernel_launch(void* const* d_in, const int* in_sizes, int n_in,
                              void* d_out, int out_size, void* d_ws, size_t ws_size,
                              hipStream_t stream) {
  const float* x     = (const float*)d_in[0];
  const int*   ei    = (const int*)d_in[1];
  const int*   batch = (const int*)d_in[2];
  const float* W1    = (const float*)d_in[3];
  const float* asrc1 = (const float*)d_in[4];
  const float* adst1 = (const float*)d_in[5];
  const float* b1    = (const float*)d_in[6];
  const float* W2    = (const float*)d_in[7];
  const float* asrc2 = (const float*)d_in[8];
  const float* adst2 = (const float*)d_in[9];
  const float* b2    = (const float*)d_in[10];
  const float* fcw   = (const float*)d_in[11];
  const float* fcb   = (const float*)d_in[12];
  float* out = (float*)d_out;

  char* w = (char*)d_ws;
  size_t off = 0;
  auto alloc = [&](size_t bytes) -> char* {
    char* p = w + off;
    off = (off + bytes + 255) & ~(size_t)255;
    return p;
  };
  int* counts    = (int*)alloc((size_t)N_NODES * 4);
  int* row_ptr   = (int*)alloc((size_t)(N_NODES + 1) * 4);
  int* nxt       = (int*)alloc((size_t)N_NODES * 4);
  int* csr_src   = (int*)alloc((size_t)E_TOT * 4);
  int* partial   = (int*)alloc(NCHUNK * 4);
  int* chunk_off = (int*)alloc(NCHUNK * 4);
  float* als1    = (float*)alloc((size_t)N_NODES * NH1 * 4);
  float* ald1    = (float*)alloc((size_t)N_NODES * NH1 * 4);
  float* als2    = (float*)alloc((size_t)N_NODES * 4);
  float* ald2    = (float*)alloc((size_t)N_NODES * 4);
  u32*   pool    = (u32*)alloc((size_t)N_GRAPHS * D2 * 4);
  float* w_als   = (float*)alloc((size_t)D1 * 4);
  float* w_ald   = (float*)alloc((size_t)D1 * 4);
  u32*   W1t2    = (u32*)alloc((size_t)D1 * (F_IN / 2) * 4);
  u32*   W2h     = (u32*)alloc((size_t)(D1 / 2) * D2 * 4);
  u32*   xh2     = (u32*)alloc((size_t)N_NODES * XW * 4);
  u32*   aggx2   = (u32*)alloc((size_t)N_NODES * (D1 / 2) * 4);
  __half* hacth  = (__half*)alloc((size_t)N_NODES * D1 * 2);
  __half* h2h    = (__half*)alloc((size_t)N_NODES * D2 * 2);

  k_init<<<dim3(196), dim3(256), 0, stream>>>(counts, pool);
  k_hist<<<dim3((E_TOT + 255) / 256), dim3(256), 0, stream>>>(ei, counts);
  k_scan1<<<dim3(NCHUNK), dim3(256), 0, stream>>>(counts, partial);
  k_scan2<<<dim3(1), dim3(64), 0, stream>>>(partial, chunk_off, row_ptr);
  k_scan3<<<dim3(NCHUNK), dim3(SCHUNK), 0, stream>>>(counts, chunk_off, row_ptr, nxt);
  k_scatter<<<dim3((E_TOT + 255) / 256), dim3(256), 0, stream>>>(ei, nxt, csr_src);
  k_prep<<<dim3(117), dim3(256), 0, stream>>>(W1, asrc1, adst1, W2, w_als, w_ald, W1t2, W2h);

  k_als1<<<dim3((N_NODES + 63) / 64), dim3(256), 0, stream>>>(x, w_als, w_ald, als1, ald1, xh2);
  k_agg1<<<dim3(N_NODES / 4), dim3(256), 0, stream>>>(xh2, als1, ald1, row_ptr, csr_src, aggx2);
  k_mix1<<<dim3((N_NODES + MIX_NPB - 1) / MIX_NPB), dim3(384), 0, stream>>>(aggx2, W1t2, b1, hacth);

  k_gemm2<<<dim3(N_NODES / G2_NPB), dim3(256), 0, stream>>>(hacth, W2h, h2h);
  k_als2<<<dim3(N_NODES / 4), dim3(256), 0, stream>>>(h2h, asrc2, adst2, als2, ald2);
  k_agg2<<<dim3(N_NODES / 4), dim3(256), 0, stream>>>(h2h, als2, ald2, row_ptr, csr_src,
                                                      b2, batch, pool);

  k_final<<<dim3(N_GRAPHS), dim3(D2), 0, stream>>>((const float*)pool, fcw, fcb, out);

  (void)in_sizes; (void)n_in; (void)out_size; (void)ws_size;
}